// Round 1
// baseline (280.461 us; speedup 1.0000x reference)
//
#include <hip/hip_runtime.h>
#include <stdint.h>

// ---------------------------------------------------------------------------
// Fused MHA: proj(Q,K,V) -> flash attention (split-K over T) -> combine -> out proj
// All GEMMs via v_mfma_f32_16x16x32_bf16.
// Fragment layouts (gfx950):
//   A (M=16,K=32): row = lane&15, k = 8*(lane>>4) + j   (8 contiguous bf16 -> 1 b128)
//   B (K=32,N=16): col = lane&15, k = 8*(lane>>4) + j   (read from B^T row-major)
//   C/D:           col = lane&15, row = 4*(lane>>4) + reg  [HW-verified, learn_hip m89]
// ---------------------------------------------------------------------------

typedef float f32x4 __attribute__((ext_vector_type(4)));
typedef __bf16 bf16x8 __attribute__((ext_vector_type(8)));

__device__ __forceinline__ unsigned short f2bf(float f) {
  unsigned int u = __builtin_bit_cast(unsigned int, f);
  u += 0x7FFFu + ((u >> 16) & 1u);          // round-to-nearest-even
  return (unsigned short)(u >> 16);
}

__device__ __forceinline__ f32x4 mfma16(bf16x8 a, bf16x8 b, f32x4 c) {
  return __builtin_amdgcn_mfma_f32_16x16x32_bf16(a, b, c, 0, 0, 0);
}

// ---------------------------------------------------------------------------
// Projection: out[h][n][d] = bf16( (X[n,:] @ W[:,h*32+d] + bias) * scale )
// X fp32 [N][256], W fp32 [256][256]. Block: 64 rows x 256 cols, 4 waves.
// ---------------------------------------------------------------------------
__global__ __launch_bounds__(256) void proj_kernel(
    const float* __restrict__ X, const float* __restrict__ W,
    const float* __restrict__ bias, unsigned short* __restrict__ out,
    int N, float scale)
{
  const int tid = threadIdx.x;
  const int w = tid >> 6, lane = tid & 63, g = lane >> 4, c = lane & 15;
  const int m0 = blockIdx.x * 64;

  __shared__ __align__(16) unsigned short Xs[64 * 40];   // 64 rows x 32 k, pad 40
  __shared__ __align__(16) unsigned short Ws[32 * 258];  // 32 k x 256 cols, pad 258

  const f32x4 zero4 = {0.f, 0.f, 0.f, 0.f};
  f32x4 acc[4][4];
  #pragma unroll
  for (int i = 0; i < 4; ++i)
    #pragma unroll
    for (int j = 0; j < 4; ++j) acc[i][j] = zero4;

  const int srow = tid >> 2;        // 0..63
  const int sks  = (tid & 3) * 8;   // 0,8,16,24

  for (int k0 = 0; k0 < 256; k0 += 32) {
    __syncthreads();
    { // stage X chunk as bf16 (one b128 LDS write per thread)
      const float* xp = X + (size_t)(m0 + srow) * 256 + k0 + sks;
      float4 x0 = *(const float4*)xp;
      float4 x1 = *(const float4*)(xp + 4);
      int4 pk;
      pk.x = (int)f2bf(x0.x) | ((int)f2bf(x0.y) << 16);
      pk.y = (int)f2bf(x0.z) | ((int)f2bf(x0.w) << 16);
      pk.z = (int)f2bf(x1.x) | ((int)f2bf(x1.y) << 16);
      pk.w = (int)f2bf(x1.z) | ((int)f2bf(x1.w) << 16);
      *(int4*)&Xs[srow * 40 + sks] = pk;
    }
    #pragma unroll
    for (int i = 0; i < 32; ++i)   // stage W chunk, coalesced rows
      Ws[i * 258 + tid] = f2bf(W[(size_t)(k0 + i) * 256 + tid]);
    __syncthreads();

    bf16x8 a[4], b[4];
    #pragma unroll
    for (int rt = 0; rt < 4; ++rt)
      a[rt] = *(const bf16x8*)&Xs[(16 * rt + c) * 40 + 8 * g];
    #pragma unroll
    for (int ct = 0; ct < 4; ++ct) {
      union { unsigned short u[8]; bf16x8 v; } t;
      #pragma unroll
      for (int j = 0; j < 8; ++j)
        t.u[j] = Ws[(8 * g + j) * 258 + 64 * w + 16 * ct + c];
      b[ct] = t.v;
    }
    #pragma unroll
    for (int rt = 0; rt < 4; ++rt)
      #pragma unroll
      for (int ct = 0; ct < 4; ++ct)
        acc[rt][ct] = mfma16(a[rt], b[ct], acc[rt][ct]);
  }

  #pragma unroll
  for (int ct = 0; ct < 4; ++ct) {
    const int col = 64 * w + 16 * ct + c;
    const float bv = bias[col];
    const int hh = col >> 5, d = col & 31;
    #pragma unroll
    for (int rt = 0; rt < 4; ++rt)
      #pragma unroll
      for (int r = 0; r < 4; ++r) {
        const int row = m0 + 16 * rt + 4 * g + r;
        const float v = (acc[rt][ct][r] + bv) * scale;
        out[((size_t)hh * N + row) * 32 + d] = f2bf(v);
      }
  }
}

// ---------------------------------------------------------------------------
// Flash attention, one head per blockIdx.y, split-K (T) over blockIdx.z.
// Block = 64 queries (4 waves x 16 rows), BN=64 keys per iteration.
// ---------------------------------------------------------------------------
__global__ __launch_bounds__(256) void attn_kernel(
    const unsigned short* __restrict__ qh, const unsigned short* __restrict__ kh,
    const unsigned short* __restrict__ vh,
    float* __restrict__ part_o, float* __restrict__ part_m, float* __restrict__ part_l)
{
  const int qb = blockIdx.x, h = blockIdx.y, sp = blockIdx.z;
  const int tid = threadIdx.x;
  const int w = tid >> 6, lane = tid & 63, g = lane >> 4, c = lane & 15;
  const int q0 = qb * 64 + w * 16;

  __shared__ __align__(16) unsigned short Ks[64 * 40];    // [key][32] pad 40
  __shared__ __align__(16) unsigned short Vt[32 * 72];    // V^T: [vd][64] pad 72
  __shared__ __align__(16) unsigned short Ps[4][16 * 72]; // per-wave P: [16 q][64] pad 72

  // Q fragment (scale folded in at projection): A row = c, k = 8g+j
  const bf16x8 qa = *(const bf16x8*)&qh[((size_t)h * 2048 + q0 + c) * 32 + 8 * g];

  const f32x4 zero4 = {0.f, 0.f, 0.f, 0.f};
  f32x4 acc0 = zero4, acc1 = zero4;       // O tiles: vd = c, vd = 16+c ; rows 4g+r
  float mrow[4], lrow[4];
  #pragma unroll
  for (int r = 0; r < 4; ++r) { mrow[r] = -1e30f; lrow[r] = 0.f; }

  const int skey = tid >> 2;
  const int sseg = (tid & 3) * 8;
  const unsigned short* kb0 = kh + (size_t)h * 16384 * 32;
  const unsigned short* vb0 = vh + (size_t)h * 16384 * 32;

  for (int it = 0; it < 64; ++it) {
    const int t0 = sp * 4096 + it * 64;
    __syncthreads();   // prev iteration's reads of Ks/Vt complete
    {
      int4 kv = *(const int4*)&kb0[(size_t)(t0 + skey) * 32 + sseg];
      *(int4*)&Ks[skey * 40 + sseg] = kv;
      int4 vv = *(const int4*)&vb0[(size_t)(t0 + skey) * 32 + sseg];
      const unsigned short* pv = (const unsigned short*)&vv;
      #pragma unroll
      for (int j = 0; j < 8; ++j) Vt[(sseg + j) * 72 + skey] = pv[j];
    }
    __syncthreads();

    // S = Q K^T : 4 col-tiles of 16 keys, full K=32 per MFMA
    f32x4 st[4];
    #pragma unroll
    for (int ct = 0; ct < 4; ++ct) {
      bf16x8 kbf = *(const bf16x8*)&Ks[(16 * ct + c) * 40 + 8 * g];
      st[ct] = mfma16(qa, kbf, zero4);
    }

    // online softmax over this 64-key block (rows live on lanes sharing g)
    float pm[4];
    #pragma unroll
    for (int r = 0; r < 4; ++r)
      pm[r] = fmaxf(fmaxf(st[0][r], st[1][r]), fmaxf(st[2][r], st[3][r]));
    #pragma unroll
    for (int msk = 1; msk < 16; msk <<= 1)
      #pragma unroll
      for (int r = 0; r < 4; ++r)
        pm[r] = fmaxf(pm[r], __shfl_xor(pm[r], msk));

    float corr[4];
    #pragma unroll
    for (int r = 0; r < 4; ++r) {
      const float mn = fmaxf(mrow[r], pm[r]);
      corr[r] = __expf(mrow[r] - mn);
      mrow[r] = mn;
    }
    float rs[4] = {0.f, 0.f, 0.f, 0.f};
    #pragma unroll
    for (int ct = 0; ct < 4; ++ct)
      #pragma unroll
      for (int r = 0; r < 4; ++r) {
        const float p = __expf(st[ct][r] - mrow[r]);
        rs[r] += p;
        Ps[w][(4 * g + r) * 72 + 16 * ct + c] = f2bf(p);  // D-layout -> LDS
      }
    #pragma unroll
    for (int msk = 1; msk < 16; msk <<= 1)
      #pragma unroll
      for (int r = 0; r < 4; ++r)
        rs[r] += __shfl_xor(rs[r], msk);
    #pragma unroll
    for (int r = 0; r < 4; ++r) {
      lrow[r] = lrow[r] * corr[r] + rs[r];
      acc0[r] *= corr[r];
      acc1[r] *= corr[r];
    }

    // O += P V : A-frags re-read from LDS transposed, B-frags from V^T
    #pragma unroll
    for (int kc = 0; kc < 2; ++kc) {
      bf16x8 pa  = *(const bf16x8*)&Ps[w][c * 72 + 32 * kc + 8 * g];
      bf16x8 v0f = *(const bf16x8*)&Vt[c * 72 + 32 * kc + 8 * g];
      bf16x8 v1f = *(const bf16x8*)&Vt[(16 + c) * 72 + 32 * kc + 8 * g];
      acc0 = mfma16(pa, v0f, acc0);
      acc1 = mfma16(pa, v1f, acc1);
    }
  }

  // unnormalized partials
  const size_t base = (size_t)(sp * 8 + h) * 2048;
  #pragma unroll
  for (int r = 0; r < 4; ++r) {
    const int q = q0 + 4 * g + r;
    part_o[(base + q) * 32 + c]      = acc0[r];
    part_o[(base + q) * 32 + 16 + c] = acc1[r];
    if (c == 0) { part_m[base + q] = mrow[r]; part_l[base + q] = lrow[r]; }
  }
}

// ---------------------------------------------------------------------------
// Combine the 4 T-splits: softmax-rescale + normalize -> attnb bf16 [TQ][256]
// ---------------------------------------------------------------------------
__global__ __launch_bounds__(256) void combine_kernel(
    const float* __restrict__ part_o, const float* __restrict__ part_m,
    const float* __restrict__ part_l, unsigned short* __restrict__ attnb)
{
  const int gid = blockIdx.x * 256 + threadIdx.x;   // 0 .. 8*2048*32-1
  const int d = gid & 31, q = (gid >> 5) & 2047, h = gid >> 16;
  float m[4], l[4];
  #pragma unroll
  for (int s = 0; s < 4; ++s) {
    m[s] = part_m[(size_t)(s * 8 + h) * 2048 + q];
    l[s] = part_l[(size_t)(s * 8 + h) * 2048 + q];
  }
  const float mx = fmaxf(fmaxf(m[0], m[1]), fmaxf(m[2], m[3]));
  float L = 0.f, o = 0.f;
  #pragma unroll
  for (int s = 0; s < 4; ++s) {
    const float wt = __expf(m[s] - mx);
    L += wt * l[s];
    o += wt * part_o[((size_t)(s * 8 + h) * 2048 + q) * 32 + d];
  }
  attnb[(size_t)q * 256 + h * 32 + d] = f2bf(o / L);
}

// ---------------------------------------------------------------------------
// Output projection: out = attnb(bf16) @ wo(fp32->bf16) + bo, fp32 out
// ---------------------------------------------------------------------------
__global__ __launch_bounds__(256) void oproj_kernel(
    const unsigned short* __restrict__ A, const float* __restrict__ W,
    const float* __restrict__ bias, float* __restrict__ out)
{
  const int tid = threadIdx.x;
  const int w = tid >> 6, lane = tid & 63, g = lane >> 4, c = lane & 15;
  const int m0 = blockIdx.x * 64;

  __shared__ __align__(16) unsigned short Ws[32 * 258];

  const f32x4 zero4 = {0.f, 0.f, 0.f, 0.f};
  f32x4 acc[4][4];
  #pragma unroll
  for (int i = 0; i < 4; ++i)
    #pragma unroll
    for (int j = 0; j < 4; ++j) acc[i][j] = zero4;

  for (int k0 = 0; k0 < 256; k0 += 32) {
    __syncthreads();
    #pragma unroll
    for (int i = 0; i < 32; ++i)
      Ws[i * 258 + tid] = f2bf(W[(size_t)(k0 + i) * 256 + tid]);
    __syncthreads();

    bf16x8 a[4], b[4];
    #pragma unroll
    for (int rt = 0; rt < 4; ++rt)
      a[rt] = *(const bf16x8*)&A[(size_t)(m0 + 16 * rt + c) * 256 + k0 + 8 * g];
    #pragma unroll
    for (int ct = 0; ct < 4; ++ct) {
      union { unsigned short u[8]; bf16x8 v; } t;
      #pragma unroll
      for (int j = 0; j < 8; ++j)
        t.u[j] = Ws[(8 * g + j) * 258 + 64 * w + 16 * ct + c];
      b[ct] = t.v;
    }
    #pragma unroll
    for (int rt = 0; rt < 4; ++rt)
      #pragma unroll
      for (int ct = 0; ct < 4; ++ct)
        acc[rt][ct] = mfma16(a[rt], b[ct], acc[rt][ct]);
  }

  #pragma unroll
  for (int ct = 0; ct < 4; ++ct) {
    const int col = 64 * w + 16 * ct + c;
    const float bv = bias[col];
    #pragma unroll
    for (int rt = 0; rt < 4; ++rt)
      #pragma unroll
      for (int r = 0; r < 4; ++r)
        out[(size_t)(m0 + 16 * rt + 4 * g + r) * 256 + col] = acc[rt][ct][r] + bv;
  }
}

// ---------------------------------------------------------------------------
extern "C" void kernel_launch(void* const* d_in, const int* in_sizes, int n_in,
                              void* d_out, int out_size, void* d_ws, size_t ws_size,
                              hipStream_t stream)
{
  (void)in_sizes; (void)n_in; (void)out_size; (void)ws_size;
  const float* query = (const float*)d_in[0];
  const float* key   = (const float*)d_in[1];
  const float* value = (const float*)d_in[2];
  const float* wq    = (const float*)d_in[3];
  const float* bq    = (const float*)d_in[4];
  const float* wk    = (const float*)d_in[5];
  const float* bk    = (const float*)d_in[6];
  const float* wv    = (const float*)d_in[7];
  const float* bv    = (const float*)d_in[8];
  const float* wo    = (const float*)d_in[9];
  const float* bo    = (const float*)d_in[10];
  float* out = (float*)d_out;

  unsigned char* ws = (unsigned char*)d_ws;
  unsigned short* qh    = (unsigned short*)(ws);              // 8*2048*32 bf16  (1 MB)
  unsigned short* khp   = (unsigned short*)(ws + 1048576);    // 8*16384*32 bf16 (8 MB)
  unsigned short* vhp   = (unsigned short*)(ws + 9437184);    // 8*16384*32 bf16 (8 MB)
  unsigned short* attnb = (unsigned short*)(ws + 17825792);   // 2048*256 bf16   (1 MB)
  float* part_o = (float*)(ws + 18874368);                    // 4*8*2048*32 f32 (8 MB)
  float* part_m = (float*)(ws + 27262976);                    // 4*8*2048 f32
  float* part_l = (float*)(ws + 27525120);                    // 4*8*2048 f32

  proj_kernel<<<32,  256, 0, stream>>>(query, wq, bq, qh,  2048,  0.17677669529663687f);
  proj_kernel<<<256, 256, 0, stream>>>(key,   wk, bk, khp, 16384, 1.0f);
  proj_kernel<<<256, 256, 0, stream>>>(value, wv, bv, vhp, 16384, 1.0f);
  attn_kernel<<<dim3(32, 8, 4), 256, 0, stream>>>(qh, khp, vhp, part_o, part_m, part_l);
  combine_kernel<<<2048, 256, 0, stream>>>(part_o, part_m, part_l, attnb);
  oproj_kernel<<<32, 256, 0, stream>>>(attnb, wo, bo, out);
}

// Round 3
// 117.026 us; speedup vs baseline: 2.3966x; 2.3966x over previous
//
#include <hip/hip_runtime.h>
#include <stdint.h>

// ---------------------------------------------------------------------------
// Fused MHA v3:
//   convert_w -> proj(Q,K) -> proj(V, pi-permuted V^T layout) ->
//   flash attn (swapped QK^T, static-max exp2, lane-local P, linear-LDS V^T,
//   reg-staged dbuf, split-K=4 over T) -> combine -> out proj
// MFMA v_mfma_f32_16x16x32_bf16 layouts (HW-verified r1):
//   A: row=lane&15, k=8*(lane>>4)+j ; B: col=lane&15, k=8*(lane>>4)+j
//   D: col=lane&15, row=4*(lane>>4)+reg
// P residence after swapped QK^T: lane(g,c) holds P[key=16i+4g+r][q=c] ->
// as B-operand, k=8g+j maps to key pi(8g+j), pi(k): key bits = k2 k4 k3 k1 k0.
// V^T is stored to global with key-slot sigma(t) = (t&~31) | pi^-1(t&31) so
// plain contiguous A-fragment reads deliver V[pi(k)][vd] with zero shuffling.
// ---------------------------------------------------------------------------

typedef float f32x4 __attribute__((ext_vector_type(4)));
typedef __bf16 bf16x8 __attribute__((ext_vector_type(8)));

__device__ __forceinline__ unsigned short f2bf(float f) {
  unsigned int u = __builtin_bit_cast(unsigned int, f);
  u += 0x7FFFu + ((u >> 16) & 1u);          // RNE
  return (unsigned short)(u >> 16);
}

__device__ __forceinline__ f32x4 mfma16(bf16x8 a, bf16x8 b, f32x4 c) {
  return __builtin_amdgcn_mfma_f32_16x16x32_bf16(a, b, c, 0, 0, 0);
}

__device__ __forceinline__ float ex2(float x) {
#if __has_builtin(__builtin_amdgcn_exp2f)
  return __builtin_amdgcn_exp2f(x);
#else
  return exp2f(x);
#endif
}

#define QSCALE 0.25503483f  /* log2(e)/sqrt(32) */

// ---------------------------------------------------------------------------
// Convert weights f32 [256k][256n] -> bf16 transposed [256n][256k].
// ---------------------------------------------------------------------------
__global__ __launch_bounds__(256) void convert_w_kernel(
    const float* __restrict__ wq, const float* __restrict__ wk,
    const float* __restrict__ wv, const float* __restrict__ wo,
    unsigned short* __restrict__ tq, unsigned short* __restrict__ tk,
    unsigned short* __restrict__ tv, unsigned short* __restrict__ to)
{
  const int mat = blockIdx.x >> 6, k0 = (blockIdx.x & 63) * 4, n = threadIdx.x;
  const float* src; unsigned short* dst;
  if (mat == 0) { src = wq; dst = tq; }
  else if (mat == 1) { src = wk; dst = tk; }
  else if (mat == 2) { src = wv; dst = tv; }
  else { src = wo; dst = to; }
  unsigned e0 = f2bf(src[(size_t)(k0 + 0) * 256 + n]);
  unsigned e1 = f2bf(src[(size_t)(k0 + 1) * 256 + n]);
  unsigned e2 = f2bf(src[(size_t)(k0 + 2) * 256 + n]);
  unsigned e3 = f2bf(src[(size_t)(k0 + 3) * 256 + n]);
  uint2 pk = { e0 | (e1 << 16), e2 | (e3 << 16) };
  *(uint2*)&dst[(size_t)n * 256 + k0] = pk;
}

// ---------------------------------------------------------------------------
// Projection, W given transposed bf16 [n][k]. Block: 64 rows x 128 cols.
// vmode=0: out[h][row][d] (Q/K).  vmode=1: out[h][d][sigma(row)] (V^T, permuted).
// ---------------------------------------------------------------------------
__global__ __launch_bounds__(256) void proj3_kernel(
    const float* __restrict__ X, const unsigned short* __restrict__ Wt,
    const float* __restrict__ bias, unsigned short* __restrict__ out,
    int N, float scale, int vmode)
{
  const int tid = threadIdx.x;
  const int w = tid >> 6, lane = tid & 63, g = lane >> 4, c = lane & 15;
  const int m0 = blockIdx.x * 64, cb = blockIdx.y * 128;

  __shared__ __align__(16) unsigned short Xs[64 * 40];
  __shared__ __align__(16) unsigned short Ws2[128 * 40];

  const f32x4 zero4 = {0.f, 0.f, 0.f, 0.f};
  f32x4 acc[4][2];
  #pragma unroll
  for (int i = 0; i < 4; ++i) { acc[i][0] = zero4; acc[i][1] = zero4; }

  const int srow = tid >> 2, sks = (tid & 3) * 8;
  const int wrow = tid >> 1, wseg = (tid & 1) * 16;

  for (int k0 = 0; k0 < 256; k0 += 32) {
    if (k0) __syncthreads();
    { // X chunk -> bf16 LDS
      const float* xp = X + (size_t)(m0 + srow) * 256 + k0 + sks;
      float4 x0 = *(const float4*)xp;
      float4 x1 = *(const float4*)(xp + 4);
      int4 pk;
      pk.x = (int)f2bf(x0.x) | ((int)f2bf(x0.y) << 16);
      pk.y = (int)f2bf(x0.z) | ((int)f2bf(x0.w) << 16);
      pk.z = (int)f2bf(x1.x) | ((int)f2bf(x1.y) << 16);
      pk.w = (int)f2bf(x1.z) | ((int)f2bf(x1.w) << 16);
      *(int4*)&Xs[srow * 40 + sks] = pk;
    }
    { // Wt chunk (cols cb..cb+127 as rows of Wt)
      const unsigned short* wp = Wt + (size_t)(cb + wrow) * 256 + k0 + wseg;
      int4 w0 = *(const int4*)wp;
      int4 w1 = *(const int4*)(wp + 8);
      *(int4*)&Ws2[wrow * 40 + wseg] = w0;
      *(int4*)&Ws2[wrow * 40 + wseg + 8] = w1;
    }
    __syncthreads();

    bf16x8 a[4], b[2];
    #pragma unroll
    for (int rt = 0; rt < 4; ++rt)
      a[rt] = *(const bf16x8*)&Xs[(16 * rt + c) * 40 + 8 * g];
    #pragma unroll
    for (int ct = 0; ct < 2; ++ct)
      b[ct] = *(const bf16x8*)&Ws2[(32 * w + 16 * ct + c) * 40 + 8 * g];
    #pragma unroll
    for (int rt = 0; rt < 4; ++rt)
      #pragma unroll
      for (int ct = 0; ct < 2; ++ct)
        acc[rt][ct] = mfma16(a[rt], b[ct], acc[rt][ct]);
  }

  #pragma unroll
  for (int ct = 0; ct < 2; ++ct) {
    const int col = cb + 32 * w + 16 * ct + c;
    const float bv = bias[col];
    const int hh = col >> 5, d = col & 31;
    #pragma unroll
    for (int rt = 0; rt < 4; ++rt)
      #pragma unroll
      for (int r = 0; r < 4; ++r) {
        const int row = m0 + 16 * rt + 4 * g + r;
        const unsigned short v = f2bf((acc[rt][ct][r] + bv) * scale);
        if (vmode) {
          // sigma(row): pi^-1 within each 32-block: k4=u3,k3=u2,k2=u4,k1k0=u1u0
          const int pr = (row & ~31) | (((row >> 3) & 1) << 4) |
                         (((row >> 2) & 1) << 3) | (((row >> 4) & 1) << 2) |
                         (row & 3);
          out[((size_t)hh * 32 + d) * (size_t)N + pr] = v;
        } else {
          out[((size_t)hh * N + row) * 32 + d] = v;
        }
      }
  }
}

// ---------------------------------------------------------------------------
// Flash attention v3. Grid (32 qb, 8 h, 4 sp). Block 256 = 4 waves x 16 q.
// ---------------------------------------------------------------------------
__global__ __launch_bounds__(256) void attn3_kernel(
    const unsigned short* __restrict__ qh, const unsigned short* __restrict__ kh,
    const unsigned short* __restrict__ vth,
    float* __restrict__ part_o, float* __restrict__ part_l)
{
  const int qb = blockIdx.x, h = blockIdx.y, sp = blockIdx.z;
  const int tid = threadIdx.x;
  const int w = tid >> 6, lane = tid & 63, g = lane >> 4, c = lane & 15;
  const int q0 = qb * 64 + w * 16;

  __shared__ __align__(16) unsigned short Ks[64 * 40];  // [key][32] pad 40
  __shared__ __align__(16) unsigned short Vt[32 * 72];  // [vd][64 key-slots] pad 72

  // Q as B-operand: col=c=q, k=8g+j (log2e/sqrt(32) folded at projection)
  const bf16x8 qf = *(const bf16x8*)&qh[((size_t)h * 2048 + q0 + c) * 32 + 8 * g];

  const f32x4 zero4 = {0.f, 0.f, 0.f, 0.f};
  f32x4 acc0 = zero4, acc1 = zero4;   // O^T: rows vd=4g+r (+16), col q=c
  float l = 0.f;

  const int skey = tid >> 2, sseg = (tid & 3) * 8;
  const int kwoff = skey * 40 + sseg;
  const int vrow = tid >> 3, vseg = (tid & 7) * 8;
  const int vwoff = vrow * 72 + vseg;

  const unsigned short* kp = kh + (size_t)h * 524288 +
                             ((size_t)(sp * 4096) + skey) * 32 + sseg;
  const unsigned short* vp = vth + ((size_t)h * 32 + vrow) * 16384 +
                             sp * 4096 + vseg;

  int4 kA = *(const int4*)kp;  int4 vA = *(const int4*)vp;   // tile 0
  kp += 2048; vp += 64;
  int4 kB, vB;

  auto compute = [&]() {
    bf16x8 kf0 = *(const bf16x8*)&Ks[(c) * 40 + 8 * g];
    bf16x8 kf1 = *(const bf16x8*)&Ks[(16 + c) * 40 + 8 * g];
    bf16x8 kf2 = *(const bf16x8*)&Ks[(32 + c) * 40 + 8 * g];
    bf16x8 kf3 = *(const bf16x8*)&Ks[(48 + c) * 40 + 8 * g];
    f32x4 s0 = mfma16(kf0, qf, zero4);
    f32x4 s1 = mfma16(kf1, qf, zero4);
    f32x4 s2 = mfma16(kf2, qf, zero4);
    f32x4 s3 = mfma16(kf3, qf, zero4);
    // V^T fragments: plain b128, key-slots already pi-ordered in memory
    bf16x8 v00 = *(const bf16x8*)&Vt[c * 72 + 8 * g];
    bf16x8 v01 = *(const bf16x8*)&Vt[c * 72 + 32 + 8 * g];
    bf16x8 v10 = *(const bf16x8*)&Vt[(16 + c) * 72 + 8 * g];
    bf16x8 v11 = *(const bf16x8*)&Vt[(16 + c) * 72 + 32 + 8 * g];
    float rs = 0.f;
    union { __bf16 b[8]; bf16x8 v; } pa0, pa1;
    #pragma unroll
    for (int r = 0; r < 4; ++r) {
      float p0 = ex2(s0[r]), p1 = ex2(s1[r]);
      float p2 = ex2(s2[r]), p3 = ex2(s3[r]);
      rs += (p0 + p1) + (p2 + p3);
      pa0.b[r] = (__bf16)p0; pa0.b[4 + r] = (__bf16)p1;
      pa1.b[r] = (__bf16)p2; pa1.b[4 + r] = (__bf16)p3;
    }
    rs += __shfl_xor(rs, 16);
    rs += __shfl_xor(rs, 32);
    l += rs;
    acc0 = mfma16(v00, pa0.v, acc0);
    acc1 = mfma16(v10, pa0.v, acc1);
    acc0 = mfma16(v01, pa1.v, acc0);
    acc1 = mfma16(v11, pa1.v, acc1);
  };

  for (int dit = 0; dit < 32; ++dit) {
    // ---- even tile (2*dit) ----
    __syncthreads();                       // prev compute's LDS reads done
    *(int4*)&Ks[kwoff] = kA;
    *(int4*)&Vt[vwoff] = vA;
    kB = *(const int4*)kp;  vB = *(const int4*)vp;   // tile 2*dit+1
    __syncthreads();
    compute();
    // ---- odd tile (2*dit+1) ----
    __syncthreads();
    *(int4*)&Ks[kwoff] = kB;
    *(int4*)&Vt[vwoff] = vB;
    {
      const int ka = (dit < 31) ? 2048 : 0;          // clamp tail (dummy)
      const int va = (dit < 31) ? 64 : 0;
      kA = *(const int4*)(kp + ka);  vA = *(const int4*)(vp + va);
    }
    kp += 4096; vp += 128;
    __syncthreads();
    compute();
  }

  float* po = part_o + ((size_t)((sp * 8 + h) * 2048) + q0 + c) * 32;
  #pragma unroll
  for (int r = 0; r < 4; ++r) {
    po[4 * g + r]      = acc0[r];
    po[16 + 4 * g + r] = acc1[r];
  }
  if (lane < 16)
    part_l[(size_t)((sp * 8 + h) * 2048) + q0 + lane] = l;
}

// ---------------------------------------------------------------------------
// Combine 4 splits (shared exp2 domain, no max) -> attnb bf16 [TQ][256]
// ---------------------------------------------------------------------------
__global__ __launch_bounds__(256) void combine3_kernel(
    const float* __restrict__ part_o, const float* __restrict__ part_l,
    unsigned short* __restrict__ attnb)
{
  const int gid = blockIdx.x * 256 + threadIdx.x;
  const int d = gid & 31, q = (gid >> 5) & 2047, h = gid >> 16;
  float L = 0.f, o = 0.f;
  #pragma unroll
  for (int s = 0; s < 4; ++s) {
    L += part_l[(size_t)((s * 8 + h) * 2048) + q];
    o += part_o[((size_t)((s * 8 + h) * 2048) + q) * 32 + d];
  }
  attnb[(size_t)q * 256 + h * 32 + d] = f2bf(o / L);
}

// ---------------------------------------------------------------------------
// Output projection: attnb bf16 [2048][256] @ wo (as Wt bf16 [256n][256k]) + bo
// ---------------------------------------------------------------------------
__global__ __launch_bounds__(256) void oproj3_kernel(
    const unsigned short* __restrict__ A, const unsigned short* __restrict__ Wt,
    const float* __restrict__ bias, float* __restrict__ out)
{
  const int tid = threadIdx.x;
  const int w = tid >> 6, lane = tid & 63, g = lane >> 4, c = lane & 15;
  const int m0 = blockIdx.x * 64, cb = blockIdx.y * 128;

  __shared__ __align__(16) unsigned short As[64 * 40];
  __shared__ __align__(16) unsigned short Ws2[128 * 40];

  const f32x4 zero4 = {0.f, 0.f, 0.f, 0.f};
  f32x4 acc[4][2];
  #pragma unroll
  for (int i = 0; i < 4; ++i) { acc[i][0] = zero4; acc[i][1] = zero4; }

  const int arow = tid >> 2, aseg = (tid & 3) * 8;
  const int wrow = tid >> 1, wseg = (tid & 1) * 16;

  for (int k0 = 0; k0 < 256; k0 += 32) {
    if (k0) __syncthreads();
    *(int4*)&As[arow * 40 + aseg] =
        *(const int4*)&A[(size_t)(m0 + arow) * 256 + k0 + aseg];
    {
      const unsigned short* wp = Wt + (size_t)(cb + wrow) * 256 + k0 + wseg;
      int4 w0 = *(const int4*)wp;
      int4 w1 = *(const int4*)(wp + 8);
      *(int4*)&Ws2[wrow * 40 + wseg] = w0;
      *(int4*)&Ws2[wrow * 40 + wseg + 8] = w1;
    }
    __syncthreads();

    bf16x8 a[4], b[2];
    #pragma unroll
    for (int rt = 0; rt < 4; ++rt)
      a[rt] = *(const bf16x8*)&As[(16 * rt + c) * 40 + 8 * g];
    #pragma unroll
    for (int ct = 0; ct < 2; ++ct)
      b[ct] = *(const bf16x8*)&Ws2[(32 * w + 16 * ct + c) * 40 + 8 * g];
    #pragma unroll
    for (int rt = 0; rt < 4; ++rt)
      #pragma unroll
      for (int ct = 0; ct < 2; ++ct)
        acc[rt][ct] = mfma16(a[rt], b[ct], acc[rt][ct]);
  }

  #pragma unroll
  for (int ct = 0; ct < 2; ++ct) {
    const int col = cb + 32 * w + 16 * ct + c;
    const float bv = bias[col];
    #pragma unroll
    for (int rt = 0; rt < 4; ++rt)
      #pragma unroll
      for (int r = 0; r < 4; ++r)
        out[(size_t)(m0 + 16 * rt + 4 * g + r) * 256 + col] = acc[rt][ct][r] + bv;
  }
}

// ---------------------------------------------------------------------------
// Workspace layout (total 27,656,192 B -- under v1's proven-safe 27,787,264):
//   qh     @        0  (1 MB)   bf16 [8][2048][32]
//   khp    @  1048576  (8 MB)   bf16 [8][16384][32]
//   vtp    @  9437184  (8 MB)   bf16 [8][32][16384]  (pi-permuted V^T)
//   attnb  @ 17825792  (1 MB)   bf16 [2048][256]
//   part_o @ 18874368  (8 MB)   f32  [4][8][2048][32]
//     wtq/wtk/wtv overlay part_o (dead before attn writes it)
//   part_l @ 27262976  (256 KB) f32  [4][8][2048]
//   wto    @ 27525120  (128 KB) bf16 [256][256]
// ---------------------------------------------------------------------------
extern "C" void kernel_launch(void* const* d_in, const int* in_sizes, int n_in,
                              void* d_out, int out_size, void* d_ws, size_t ws_size,
                              hipStream_t stream)
{
  (void)in_sizes; (void)n_in; (void)out_size; (void)ws_size;
  const float* query = (const float*)d_in[0];
  const float* key   = (const float*)d_in[1];
  const float* value = (const float*)d_in[2];
  const float* wq    = (const float*)d_in[3];
  const float* bq    = (const float*)d_in[4];
  const float* wk    = (const float*)d_in[5];
  const float* bk    = (const float*)d_in[6];
  const float* wv    = (const float*)d_in[7];
  const float* bv    = (const float*)d_in[8];
  const float* wo    = (const float*)d_in[9];
  const float* bo    = (const float*)d_in[10];
  float* out = (float*)d_out;

  unsigned char* ws = (unsigned char*)d_ws;
  unsigned short* qh    = (unsigned short*)(ws);
  unsigned short* khp   = (unsigned short*)(ws + 1048576);
  unsigned short* vtp   = (unsigned short*)(ws + 9437184);
  unsigned short* attnb = (unsigned short*)(ws + 17825792);
  float* part_o = (float*)(ws + 18874368);
  unsigned short* wtq = (unsigned short*)(ws + 18874368);   // overlay part_o
  unsigned short* wtk = (unsigned short*)(ws + 19005440);
  unsigned short* wtv = (unsigned short*)(ws + 19136512);
  float* part_l = (float*)(ws + 27262976);
  unsigned short* wto = (unsigned short*)(ws + 27525120);

  convert_w_kernel<<<256, 256, 0, stream>>>(wq, wk, wv, wo, wtq, wtk, wtv, wto);
  proj3_kernel<<<dim3(32, 2),  256, 0, stream>>>(query, wtq, bq, qh,  2048,  QSCALE, 0);
  proj3_kernel<<<dim3(256, 2), 256, 0, stream>>>(key,   wtk, bk, khp, 16384, 1.0f,   0);
  proj3_kernel<<<dim3(256, 2), 256, 0, stream>>>(value, wtv, bv, vtp, 16384, 1.0f,   1);
  attn3_kernel<<<dim3(32, 8, 4), 256, 0, stream>>>(qh, khp, vtp, part_o, part_l);
  combine3_kernel<<<2048, 256, 0, stream>>>(part_o, part_l, attnb);
  oproj3_kernel<<<dim3(32, 2), 256, 0, stream>>>(attnb, wto, bo, out);
}

// Round 4
// 111.582 us; speedup vs baseline: 2.5135x; 1.0488x over previous
//
#include <hip/hip_runtime.h>
#include <stdint.h>

// ---------------------------------------------------------------------------
// Fused MHA v4:
//   convert_w -> proj_all (Q,K,V one launch; V stored pi-permuted V^T) ->
//   flash attn (32 q/wave, dbuf 1-barrier/tile, swapped QK^T, static-max exp2,
//   lane-local P, split-K=8, bf16 partials, XCD swizzle) ->
//   oproj (fused combine+normalize+bias)
// MFMA v_mfma_f32_16x16x32_bf16 layouts (HW-verified r1/r3):
//   A: row=lane&15, k=8*(lane>>4)+j ; B: col=lane&15, k=8*(lane>>4)+j
//   D: col=lane&15, row=4*(lane>>4)+reg
// P residence after swapped QK^T: lane(g,c) holds P[key][q=c]; as B-operand
// k=8g+j maps to key pi(8g+j) (pi: key bits = k2 k4 k3 k1 k0). V^T is stored
// to global with key-slot sigma(t) = (t&~31) | pi^-1(t&31) so contiguous
// A-fragment reads deliver V[pi(k)][vd] directly.      [all proven in v3]
// ---------------------------------------------------------------------------

typedef float f32x4 __attribute__((ext_vector_type(4)));
typedef __bf16 bf16x8 __attribute__((ext_vector_type(8)));

__device__ __forceinline__ unsigned short f2bf(float f) {
  unsigned int u = __builtin_bit_cast(unsigned int, f);
  u += 0x7FFFu + ((u >> 16) & 1u);          // RNE
  return (unsigned short)(u >> 16);
}
__device__ __forceinline__ float bf2f(unsigned u) {
  return __builtin_bit_cast(float, u << 16);
}
__device__ __forceinline__ f32x4 mfma16(bf16x8 a, bf16x8 b, f32x4 c) {
  return __builtin_amdgcn_mfma_f32_16x16x32_bf16(a, b, c, 0, 0, 0);
}
__device__ __forceinline__ float ex2(float x) {
#if __has_builtin(__builtin_amdgcn_exp2f)
  return __builtin_amdgcn_exp2f(x);
#else
  return exp2f(x);
#endif
}
__device__ __forceinline__ uint2 pack4(f32x4 a) {
  uint2 r;
  r.x = (unsigned)f2bf(a[0]) | ((unsigned)f2bf(a[1]) << 16);
  r.y = (unsigned)f2bf(a[2]) | ((unsigned)f2bf(a[3]) << 16);
  return r;
}

#define QSCALE 0.25503483f  /* log2(e)/sqrt(32) */

// ---------------------------------------------------------------------------
// Convert weights f32 [256k][256n] -> bf16 transposed [256n][256k].
// ---------------------------------------------------------------------------
__global__ __launch_bounds__(256) void convert_w_kernel(
    const float* __restrict__ wq, const float* __restrict__ wk,
    const float* __restrict__ wv, const float* __restrict__ wo,
    unsigned short* __restrict__ tq, unsigned short* __restrict__ tk,
    unsigned short* __restrict__ tv, unsigned short* __restrict__ to)
{
  const int mat = blockIdx.x >> 6, k0 = (blockIdx.x & 63) * 4, n = threadIdx.x;
  const float* src; unsigned short* dst;
  if (mat == 0) { src = wq; dst = tq; }
  else if (mat == 1) { src = wk; dst = tk; }
  else if (mat == 2) { src = wv; dst = tv; }
  else { src = wo; dst = to; }
  unsigned e0 = f2bf(src[(size_t)(k0 + 0) * 256 + n]);
  unsigned e1 = f2bf(src[(size_t)(k0 + 1) * 256 + n]);
  unsigned e2 = f2bf(src[(size_t)(k0 + 2) * 256 + n]);
  unsigned e3 = f2bf(src[(size_t)(k0 + 3) * 256 + n]);
  uint2 pk = { e0 | (e1 << 16), e2 | (e3 << 16) };
  *(uint2*)&dst[(size_t)n * 256 + k0] = pk;
}

// ---------------------------------------------------------------------------
// All three projections in one launch. 512 thr = 8 waves; 64 rows x 256 cols.
// blockIdx.y: 0=Q (scale, N=2048), 1=K, 2=V (pi-permuted V^T store).
// ---------------------------------------------------------------------------
__global__ __launch_bounds__(512) void proj4_kernel(
    const float* __restrict__ Xq, const float* __restrict__ Xk,
    const float* __restrict__ Xv,
    const unsigned short* __restrict__ Wtq, const unsigned short* __restrict__ Wtk,
    const unsigned short* __restrict__ Wtv,
    const float* __restrict__ Bq, const float* __restrict__ Bk,
    const float* __restrict__ Bv,
    unsigned short* __restrict__ Oq, unsigned short* __restrict__ Ok,
    unsigned short* __restrict__ Ov)
{
  const int mat = blockIdx.y;
  const float* X; const unsigned short* Wt; const float* Bp; unsigned short* Op;
  int N; float scale; int vmode;
  if (mat == 0) {
    if (blockIdx.x >= 32) return;
    X = Xq; Wt = Wtq; Bp = Bq; Op = Oq; N = 2048; scale = QSCALE; vmode = 0;
  } else if (mat == 1) {
    X = Xk; Wt = Wtk; Bp = Bk; Op = Ok; N = 16384; scale = 1.f; vmode = 0;
  } else {
    X = Xv; Wt = Wtv; Bp = Bv; Op = Ov; N = 16384; scale = 1.f; vmode = 1;
  }
  const int tid = threadIdx.x;
  const int w = tid >> 6, lane = tid & 63, g = lane >> 4, c = lane & 15;
  const int m0 = blockIdx.x * 64;

  __shared__ __align__(16) unsigned short Xs[64 * 40];
  __shared__ __align__(16) unsigned short Ws[256 * 40];

  const f32x4 zero4 = {0.f, 0.f, 0.f, 0.f};
  f32x4 acc[4][2];
  #pragma unroll
  for (int i = 0; i < 4; ++i) { acc[i][0] = zero4; acc[i][1] = zero4; }

  const int xrow = tid >> 3, xseg = (tid & 7) * 4;   // 64x32 f32 -> 1 float4/thr
  const int wrow = tid >> 1, wseg = (tid & 1) * 16;  // 256x32 bf16 -> 2 int4/thr

  for (int k0 = 0; k0 < 256; k0 += 32) {
    if (k0) __syncthreads();
    {
      float4 x = *(const float4*)&X[(size_t)(m0 + xrow) * 256 + k0 + xseg];
      uint2 px = { (unsigned)f2bf(x.x) | ((unsigned)f2bf(x.y) << 16),
                   (unsigned)f2bf(x.z) | ((unsigned)f2bf(x.w) << 16) };
      *(uint2*)&Xs[xrow * 40 + xseg] = px;
    }
    {
      const unsigned short* wp = Wt + (size_t)wrow * 256 + k0 + wseg;
      int4 w0 = *(const int4*)wp;
      int4 w1 = *(const int4*)(wp + 8);
      *(int4*)&Ws[wrow * 40 + wseg] = w0;
      *(int4*)&Ws[wrow * 40 + wseg + 8] = w1;
    }
    __syncthreads();

    bf16x8 a[4], b[2];
    #pragma unroll
    for (int rt = 0; rt < 4; ++rt)
      a[rt] = *(const bf16x8*)&Xs[(16 * rt + c) * 40 + 8 * g];
    #pragma unroll
    for (int ct = 0; ct < 2; ++ct)
      b[ct] = *(const bf16x8*)&Ws[(32 * w + 16 * ct + c) * 40 + 8 * g];
    #pragma unroll
    for (int rt = 0; rt < 4; ++rt)
      #pragma unroll
      for (int ct = 0; ct < 2; ++ct)
        acc[rt][ct] = mfma16(a[rt], b[ct], acc[rt][ct]);
  }

  #pragma unroll
  for (int ct = 0; ct < 2; ++ct) {
    const int col = 32 * w + 16 * ct + c;
    const float bv = Bp[col];
    const int hh = col >> 5, d = col & 31;
    #pragma unroll
    for (int rt = 0; rt < 4; ++rt)
      #pragma unroll
      for (int r = 0; r < 4; ++r) {
        const int row = m0 + 16 * rt + 4 * g + r;
        const unsigned short v = f2bf((acc[rt][ct][r] + bv) * scale);
        if (vmode) {
          const int pr = (row & ~31) | (((row >> 3) & 1) << 4) |
                         (((row >> 2) & 1) << 3) | (((row >> 4) & 1) << 2) |
                         (row & 3);
          Op[((size_t)hh * 32 + d) * (size_t)N + pr] = v;
        } else {
          Op[((size_t)hh * N + row) * 32 + d] = v;
        }
      }
  }
}

// ---------------------------------------------------------------------------
// Flash attention v4. Grid (16 qb, 8 h, 8 sp) -> 1024 blocks, XCD-swizzled.
// Block 256 = 4 waves x 32 q (2 Q-frags/wave). 32 tiles of 64 keys per split.
// Double-buffered LDS, ONE barrier per tile. bf16 unnormalized partials out.
// ---------------------------------------------------------------------------
__global__ __launch_bounds__(256) void attn4_kernel(
    const unsigned short* __restrict__ qh, const unsigned short* __restrict__ kh,
    const unsigned short* __restrict__ vth,
    unsigned short* __restrict__ part_o, float* __restrict__ part_l)
{
  // bijective XCD swizzle: 1024 blocks, 8 XCDs -> each XCD owns 8 full (h,sp)
  // panels (16 qb-blocks sharing K/V land on one XCD's L2).
  const int f = blockIdx.x + 16 * (blockIdx.y + 8 * blockIdx.z);
  const int v = (f & 7) * 128 + (f >> 3);
  const int qb = v & 15, h = (v >> 4) & 7, sp = v >> 7;

  const int tid = threadIdx.x;
  const int w = tid >> 6, lane = tid & 63, g = lane >> 4, c = lane & 15;
  const int q0 = qb * 128 + w * 32;

  __shared__ __align__(16) unsigned short Ks[2][64 * 40];  // [key][32] pad 40
  __shared__ __align__(16) unsigned short Vt[2][32 * 72];  // [vd][64 slots] pad 72

  const bf16x8 qf0 = *(const bf16x8*)&qh[((size_t)h * 2048 + q0 + c) * 32 + 8 * g];
  const bf16x8 qf1 = *(const bf16x8*)&qh[((size_t)h * 2048 + q0 + 16 + c) * 32 + 8 * g];

  const f32x4 zero4 = {0.f, 0.f, 0.f, 0.f};
  f32x4 acc00 = zero4, acc01 = zero4, acc10 = zero4, acc11 = zero4;
  float l0 = 0.f, l1 = 0.f;

  const int skey = tid >> 2, sseg = (tid & 3) * 8;
  const int kwoff = skey * 40 + sseg;
  const int vrow = tid >> 3, vseg = (tid & 7) * 8;
  const int vwoff = vrow * 72 + vseg;

  const unsigned short* kp = kh + (size_t)h * 524288 +
                             ((size_t)(sp * 2048) + skey) * 32 + sseg;
  const unsigned short* vp = vth + ((size_t)h * 32 + vrow) * 16384 +
                             sp * 2048 + vseg;

  // prologue: stage tile 0, prefetch tile 1
  int4 kA = *(const int4*)kp;
  int4 vA = *(const int4*)vp;
  *(int4*)&Ks[0][kwoff] = kA;
  *(int4*)&Vt[0][vwoff] = vA;
  kA = *(const int4*)(kp + 2048);
  vA = *(const int4*)(vp + 64);
  __syncthreads();

  for (int it = 0; it < 32; ++it) {
    const int cur = it & 1;
    if (it < 31) {
      // write tile it+1 into the other buffer (its last readers finished at
      // the barrier ending iteration it-1), then prefetch tile it+2.
      *(int4*)&Ks[cur ^ 1][kwoff] = kA;
      *(int4*)&Vt[cur ^ 1][vwoff] = vA;
      const int t2 = (it + 2) & 31;                  // it=30 -> dummy tile 0
      kA = *(const int4*)(kp + t2 * 2048);
      vA = *(const int4*)(vp + t2 * 64);
    }

    const unsigned short* Kb = &Ks[cur][0];
    const unsigned short* Vb = &Vt[cur][0];
    bf16x8 kf0 = *(const bf16x8*)&Kb[(c) * 40 + 8 * g];
    bf16x8 kf1 = *(const bf16x8*)&Kb[(16 + c) * 40 + 8 * g];
    bf16x8 kf2 = *(const bf16x8*)&Kb[(32 + c) * 40 + 8 * g];
    bf16x8 kf3 = *(const bf16x8*)&Kb[(48 + c) * 40 + 8 * g];

    // ---- Q-frag 0 ----
    f32x4 s0 = mfma16(kf0, qf0, zero4);
    f32x4 s1 = mfma16(kf1, qf0, zero4);
    f32x4 s2 = mfma16(kf2, qf0, zero4);
    f32x4 s3 = mfma16(kf3, qf0, zero4);
    union { __bf16 b[8]; bf16x8 v; } pa00, pa01, pa10, pa11;
    float rs0 = 0.f;
    #pragma unroll
    for (int r = 0; r < 4; ++r) {
      float p0 = ex2(s0[r]), p1 = ex2(s1[r]);
      float p2 = ex2(s2[r]), p3 = ex2(s3[r]);
      rs0 += (p0 + p1) + (p2 + p3);
      pa00.b[r] = (__bf16)p0; pa00.b[4 + r] = (__bf16)p1;
      pa01.b[r] = (__bf16)p2; pa01.b[4 + r] = (__bf16)p3;
    }
    rs0 += __shfl_xor(rs0, 16);
    rs0 += __shfl_xor(rs0, 32);
    l0 += rs0;
    // ---- Q-frag 1 (reuses K frags) ----
    s0 = mfma16(kf0, qf1, zero4);
    s1 = mfma16(kf1, qf1, zero4);
    s2 = mfma16(kf2, qf1, zero4);
    s3 = mfma16(kf3, qf1, zero4);
    float rs1 = 0.f;
    #pragma unroll
    for (int r = 0; r < 4; ++r) {
      float p0 = ex2(s0[r]), p1 = ex2(s1[r]);
      float p2 = ex2(s2[r]), p3 = ex2(s3[r]);
      rs1 += (p0 + p1) + (p2 + p3);
      pa10.b[r] = (__bf16)p0; pa10.b[4 + r] = (__bf16)p1;
      pa11.b[r] = (__bf16)p2; pa11.b[4 + r] = (__bf16)p3;
    }
    rs1 += __shfl_xor(rs1, 16);
    rs1 += __shfl_xor(rs1, 32);
    l1 += rs1;

    // ---- PV: V^T fragments (pi-ordered in memory), 8 MFMAs ----
    bf16x8 v00 = *(const bf16x8*)&Vb[c * 72 + 8 * g];
    bf16x8 v01 = *(const bf16x8*)&Vb[c * 72 + 32 + 8 * g];
    bf16x8 v10 = *(const bf16x8*)&Vb[(16 + c) * 72 + 8 * g];
    bf16x8 v11 = *(const bf16x8*)&Vb[(16 + c) * 72 + 32 + 8 * g];
    __builtin_amdgcn_s_setprio(1);
    acc00 = mfma16(v00, pa00.v, acc00);
    acc01 = mfma16(v10, pa00.v, acc01);
    acc00 = mfma16(v01, pa01.v, acc00);
    acc01 = mfma16(v11, pa01.v, acc01);
    acc10 = mfma16(v00, pa10.v, acc10);
    acc11 = mfma16(v10, pa10.v, acc11);
    acc10 = mfma16(v01, pa11.v, acc10);
    acc11 = mfma16(v11, pa11.v, acc11);
    __builtin_amdgcn_s_setprio(0);

    __syncthreads();   // single barrier per tile
  }

  // epilogue: bf16 unnormalized partials
  const size_t pbase = (size_t)(sp * 8 + h) * 2048;
  unsigned short* po0 = part_o + (pbase + q0 + c) * 32;
  *(uint2*)&po0[4 * g]      = pack4(acc00);
  *(uint2*)&po0[16 + 4 * g] = pack4(acc01);
  unsigned short* po1 = part_o + (pbase + q0 + 16 + c) * 32;
  *(uint2*)&po1[4 * g]      = pack4(acc10);
  *(uint2*)&po1[16 + 4 * g] = pack4(acc11);
  if (lane < 16) {
    part_l[pbase + q0 + lane]      = l0;
    part_l[pbase + q0 + 16 + lane] = l1;
  }
}

// ---------------------------------------------------------------------------
// Output projection with fused split-combine + per-(h,q) normalization + bias.
// 512 thr = 8 waves; 64 rows x 256 cols; chunk k0 <-> head h = k0>>5.
// ---------------------------------------------------------------------------
__global__ __launch_bounds__(512) void oproj4_kernel(
    const unsigned short* __restrict__ part_o, const float* __restrict__ part_l,
    const unsigned short* __restrict__ Wt, const float* __restrict__ bias,
    float* __restrict__ out)
{
  const int tid = threadIdx.x;
  const int w = tid >> 6, lane = tid & 63, g = lane >> 4, c = lane & 15;
  const int m0 = blockIdx.x * 64;

  __shared__ __align__(16) unsigned short As[64 * 40];
  __shared__ __align__(16) unsigned short Ws[256 * 40];

  const f32x4 zero4 = {0.f, 0.f, 0.f, 0.f};
  f32x4 acc[4][2];
  #pragma unroll
  for (int i = 0; i < 4; ++i) { acc[i][0] = zero4; acc[i][1] = zero4; }

  const int arow = tid >> 3, aseg = (tid & 7) * 4;   // 64 rows x 32 d
  const int wrow = tid >> 1, wseg = (tid & 1) * 16;

  for (int k0 = 0; k0 < 256; k0 += 32) {
    const int h = k0 >> 5;
    if (k0) __syncthreads();
    { // combine 8 splits, normalize by L, pack to bf16
      float L = 0.f;
      float o0 = 0.f, o1 = 0.f, o2 = 0.f, o3 = 0.f;
      #pragma unroll
      for (int s = 0; s < 8; ++s) {
        const size_t b = (size_t)(s * 8 + h) * 2048 + m0 + arow;
        L += part_l[b];
        uint2 pk = *(const uint2*)&part_o[b * 32 + aseg];
        o0 += bf2f(pk.x & 0xffffu); o1 += bf2f(pk.x >> 16);
        o2 += bf2f(pk.y & 0xffffu); o3 += bf2f(pk.y >> 16);
      }
      const float inv = 1.f / L;
      uint2 pa = { (unsigned)f2bf(o0 * inv) | ((unsigned)f2bf(o1 * inv) << 16),
                   (unsigned)f2bf(o2 * inv) | ((unsigned)f2bf(o3 * inv) << 16) };
      *(uint2*)&As[arow * 40 + aseg] = pa;
    }
    {
      const unsigned short* wp = Wt + (size_t)wrow * 256 + k0 + wseg;
      int4 w0 = *(const int4*)wp;
      int4 w1 = *(const int4*)(wp + 8);
      *(int4*)&Ws[wrow * 40 + wseg] = w0;
      *(int4*)&Ws[wrow * 40 + wseg + 8] = w1;
    }
    __syncthreads();

    bf16x8 a[4], b[2];
    #pragma unroll
    for (int rt = 0; rt < 4; ++rt)
      a[rt] = *(const bf16x8*)&As[(16 * rt + c) * 40 + 8 * g];
    #pragma unroll
    for (int ct = 0; ct < 2; ++ct)
      b[ct] = *(const bf16x8*)&Ws[(32 * w + 16 * ct + c) * 40 + 8 * g];
    #pragma unroll
    for (int rt = 0; rt < 4; ++rt)
      #pragma unroll
      for (int ct = 0; ct < 2; ++ct)
        acc[rt][ct] = mfma16(a[rt], b[ct], acc[rt][ct]);
  }

  #pragma unroll
  for (int ct = 0; ct < 2; ++ct) {
    const int col = 32 * w + 16 * ct + c;
    const float bv = bias[col];
    #pragma unroll
    for (int rt = 0; rt < 4; ++rt)
      #pragma unroll
      for (int r = 0; r < 4; ++r)
        out[(size_t)(m0 + 16 * rt + 4 * g + r) * 256 + col] = acc[rt][ct][r] + bv;
  }
}

// ---------------------------------------------------------------------------
// Workspace (total 26,869,760 B -- under v3's proven 27,656,192):
//   qh     @        0  (1 MB)    bf16 [8][2048][32]
//   khp    @  1048576  (8 MB)    bf16 [8][16384][32]
//   vtp    @  9437184  (8 MB)    bf16 [8][32][16384]  (pi-permuted V^T)
//   part_o @ 17825792  (8 MB)    bf16 [8sp][8h][2048][32]  (unnormalized)
//     wtq/wtk/wtv overlay part_o (dead before attn writes it)
//   part_l @ 26214400  (512 KB)  f32  [8sp][8h][2048]
//   wto    @ 26738688  (128 KB)  bf16 [256][256]
// ---------------------------------------------------------------------------
extern "C" void kernel_launch(void* const* d_in, const int* in_sizes, int n_in,
                              void* d_out, int out_size, void* d_ws, size_t ws_size,
                              hipStream_t stream)
{
  (void)in_sizes; (void)n_in; (void)out_size; (void)ws_size;
  const float* query = (const float*)d_in[0];
  const float* key   = (const float*)d_in[1];
  const float* value = (const float*)d_in[2];
  const float* wq    = (const float*)d_in[3];
  const float* bq    = (const float*)d_in[4];
  const float* wk    = (const float*)d_in[5];
  const float* bk    = (const float*)d_in[6];
  const float* wv    = (const float*)d_in[7];
  const float* bv    = (const float*)d_in[8];
  const float* wo    = (const float*)d_in[9];
  const float* bo    = (const float*)d_in[10];
  float* out = (float*)d_out;

  unsigned char* ws = (unsigned char*)d_ws;
  unsigned short* qh     = (unsigned short*)(ws);
  unsigned short* khp    = (unsigned short*)(ws + 1048576);
  unsigned short* vtp    = (unsigned short*)(ws + 9437184);
  unsigned short* part_o = (unsigned short*)(ws + 17825792);
  unsigned short* wtq    = (unsigned short*)(ws + 17825792);  // overlay part_o
  unsigned short* wtk    = (unsigned short*)(ws + 17956864);
  unsigned short* wtv    = (unsigned short*)(ws + 18087936);
  float*          part_l = (float*)(ws + 26214400);
  unsigned short* wto    = (unsigned short*)(ws + 26738688);

  convert_w_kernel<<<256, 256, 0, stream>>>(wq, wk, wv, wo, wtq, wtk, wtv, wto);
  proj4_kernel<<<dim3(256, 3), 512, 0, stream>>>(
      query, key, value, wtq, wtk, wtv, bq, bk, bv, qh, khp, vtp);
  attn4_kernel<<<dim3(16, 8, 8), 256, 0, stream>>>(qh, khp, vtp, part_o, part_l);
  oproj4_kernel<<<32, 512, 0, stream>>>(part_o, part_l, wto, bo, out);
}